// Round 14
// baseline (273.374 us; speedup 1.0000x reference)
//
#include <hip/hip_runtime.h>
#include <stdint.h>

#define B_GRAPHS 2048
#define CHUNK 256                    // fallback path: graphs per chunk
#define E_PER 512
#define D_USER 32
#define HID 512
#define GK 4160                      // states dim = 64*64 + 64
#define STATES_DIM 4160
#define WS_FALLBACK 6356992
#define WS_FAST 23396352

typedef unsigned short u16;
typedef unsigned int u32;
typedef __attribute__((ext_vector_type(8))) short short8;   // 8 bf16 (4 VGPRs)
typedef __attribute__((ext_vector_type(4))) float f32x4;    // MFMA accumulator

// ---------------- bf16 helpers ----------------------------------------------
__device__ __forceinline__ float bf2f(u16 b) {
    union { uint32_t u; float f; } c; c.u = ((uint32_t)b) << 16; return c.f;
}
__device__ __forceinline__ u16 f2bf(float f) {   // round-to-nearest-even
    union { float f; uint32_t u; } c; c.f = f;
    uint32_t u = c.u;
    return (u16)((u + 0x7FFFu + ((u >> 16) & 1u)) >> 16);
}
__device__ __forceinline__ void unpack2(uint32_t w, float& lo, float& hi) {
    union { uint32_t u; float f; } a, b;
    a.u = w << 16; b.u = w & 0xFFFF0000u;
    lo = a.f; hi = b.f;
}

// ---------------- threefry2x32, key=(0,42), partitionable (proven R9) -------
__device__ __forceinline__ uint32_t rotl32(uint32_t v, int r) {
    return (v << r) | (v >> (32 - r));
}
__device__ __forceinline__ void threefry_0_42(uint32_t x0, uint32_t x1,
                                              uint32_t& o0, uint32_t& o1) {
    const uint32_t ks0 = 0u, ks1 = 42u, ks2 = 0x1BD11BDAu ^ 42u;
    x0 += ks0; x1 += ks1;
#define TFR(r) { x0 += x1; x1 = rotl32(x1, (r)); x1 ^= x0; }
    TFR(13) TFR(15) TFR(26) TFR(6)
    x0 += ks1; x1 += ks2 + 1u;
    TFR(17) TFR(29) TFR(16) TFR(24)
    x0 += ks2; x1 += ks0 + 2u;
    TFR(13) TFR(15) TFR(26) TFR(6)
    x0 += ks0; x1 += ks1 + 3u;
    TFR(17) TFR(29) TFR(16) TFR(24)
    x0 += ks1; x1 += ks2 + 4u;
    TFR(13) TFR(15) TFR(26) TFR(6)
    x0 += ks2; x1 += ks0 + 5u;
#undef TFR
    o0 = x0; o1 = x1;
}
__device__ __forceinline__ bool keep_bit(uint32_t j) {
    uint32_t o0, o1;
    threefry_0_42(0u, j, o0, o1);
    return (((o0 ^ o1) >> 31) == 0u);
}

// ------------- mask kernel: 64 keep-bits per u64 word -----------------------
__global__ __launch_bounds__(256) void mask_kernel(unsigned long long* __restrict__ mask) {
    uint32_t j = blockIdx.x * 256u + threadIdx.x;    // 0 .. 8388607
    uint32_t o0, o1;
    threefry_0_42(0u, j, o0, o1);
    unsigned long long b = __ballot(((o0 ^ o1) >> 31) == 0u);
    if ((threadIdx.x & 63u) == 0u) mask[j >> 6] = b;
}

// ------------- diagnostic fill ----------------------------------------------
__global__ __launch_bounds__(256) void fill_kernel(float* __restrict__ out, float v, int n) {
    int i = blockIdx.x * 256 + threadIdx.x;
    if (i < n) out[i] = v;
}

// ------------- FAST node kernel (proven R12) --------------------------------
__global__ __launch_bounds__(256) void node_fast(
    const float* __restrict__ x, const float* __restrict__ edge_attr,
    const float* __restrict__ user_s,
    const float* __restrict__ W_msg, const float* __restrict__ b_msg,
    const float* __restrict__ W_edge, const float* __restrict__ b_edge,
    const float* __restrict__ W_self, const float* __restrict__ b_self,
    const float* __restrict__ W1, const float* __restrict__ b1,
    const int* __restrict__ src, const int* __restrict__ dst,
    const unsigned long long* __restrict__ mask,
    u16* __restrict__ states)
{
    const int g = blockIdx.x;
    const int tid = threadIdx.x;
    const int w = tid >> 6, lane = tid & 63;

    __shared__ float sx[64][16];       // [s][k]
    __shared__ u32   scnt[64][64];     // [s][d]  adjacency counts
    __shared__ float sxsum[64][16];    // [d][k]
    __shared__ float sesum[2][64];     // [j][d]
    __shared__ float sdeg[64];
    __shared__ unsigned long long smask[64];

    float rWmsg[16], rWself[16];
    #pragma unroll
    for (int k = 0; k < 16; ++k) {
        rWmsg[k]  = W_msg[k * 64 + lane];
        rWself[k] = W_self[k * 64 + lane];
    }
    const float rWe0   = W_edge[lane];
    const float rWe1   = W_edge[64 + lane];
    const float rbias  = b_msg[lane] + b_edge[lane];
    const float rbself = b_self[lane];

    const float* xg = x + (size_t)g * 1024;
    for (int i = tid; i < 1024; i += 256) ((float*)sx)[i] = xg[i];
    {
        uint4 z = make_uint4(0, 0, 0, 0);
        u32* c0 = &scnt[0][0] + tid * 16;
        *(uint4*)(c0 + 0)  = z; *(uint4*)(c0 + 4)  = z;
        *(uint4*)(c0 + 8)  = z; *(uint4*)(c0 + 12) = z;
    }
    if (tid < 64) {
        sesum[0][tid] = 0.f; sesum[1][tid] = 0.f;
        smask[tid] = mask[g * 64 + tid];
    }
    __syncthreads();

    const float2* ea2 = (const float2*)edge_attr;
    for (int e = tid; e < E_PER; e += 256) {
        int ge = g * E_PER + e;
        int s = src[ge] - g * 64;
        int d = dst[ge] - g * 64;
        float2 a = ea2[ge];
        atomicAdd(&scnt[s][d], 1u);
        atomicAdd(&sesum[0][d], a.x);
        atomicAdd(&sesum[1][d], a.y);
    }
    __syncthreads();

    {   // dense MAC: sxsum[d][kg*4..+3] = sum_s cnt[s][d] * x[s][kg*4..+3]
        const int d = tid >> 2, kg = tid & 3;
        float4 acc = make_float4(0.f, 0.f, 0.f, 0.f);
        float dg = 0.f;
        #pragma unroll 8
        for (int s = 0; s < 64; ++s) {
            float c = (float)scnt[s][d];
            dg += c;
            float4 xv = *(const float4*)&sx[s][kg * 4];
            acc.x += c * xv.x; acc.y += c * xv.y;
            acc.z += c * xv.z; acc.w += c * xv.w;
        }
        *(float4*)&sxsum[d][kg * 4] = acc;
        if (kg == 0) sdeg[d] = dg;
    }
    __syncthreads();

    u16* out = states + (size_t)g * STATES_DIM;
    #pragma unroll
    for (int i = 0; i < 16; ++i) {
        const int n = 4 * i + w;                       // wave-uniform node
        float v = rbself + sdeg[n] * rbias
                + sesum[0][n] * rWe0 + sesum[1][n] * rWe1;
        float4 s0 = *(const float4*)&sxsum[n][0];
        float4 s1 = *(const float4*)&sxsum[n][4];
        float4 s2 = *(const float4*)&sxsum[n][8];
        float4 s3 = *(const float4*)&sxsum[n][12];
        float4 x0 = *(const float4*)&sx[n][0];
        float4 x1 = *(const float4*)&sx[n][4];
        float4 x2 = *(const float4*)&sx[n][8];
        float4 x3 = *(const float4*)&sx[n][12];
        v += s0.x*rWmsg[0]  + s0.y*rWmsg[1]  + s0.z*rWmsg[2]  + s0.w*rWmsg[3]
           + s1.x*rWmsg[4]  + s1.y*rWmsg[5]  + s1.z*rWmsg[6]  + s1.w*rWmsg[7]
           + s2.x*rWmsg[8]  + s2.y*rWmsg[9]  + s2.z*rWmsg[10] + s2.w*rWmsg[11]
           + s3.x*rWmsg[12] + s3.y*rWmsg[13] + s3.z*rWmsg[14] + s3.w*rWmsg[15]
           + x0.x*rWself[0]  + x0.y*rWself[1]  + x0.z*rWself[2]  + x0.w*rWself[3]
           + x1.x*rWself[4]  + x1.y*rWself[5]  + x1.z*rWself[6]  + x1.w*rWself[7]
           + x2.x*rWself[8]  + x2.y*rWself[9]  + x2.z*rWself[10] + x2.w*rWself[11]
           + x3.x*rWself[12] + x3.y*rWself[13] + x3.z*rWself[14] + x3.w*rWself[15];
        v = v > 0.f ? v : 0.f;                         // relu
        unsigned long long m = smask[n];
        v = ((m >> lane) & 1ull) ? v * 2.0f : 0.0f;    // dropout p=0.5
        out[n * 64 + lane] = f2bf(v);
    }
    if (tid < 64) {                                    // user = relu(u @ W1 + b1)
        float v = b1[tid];
        const float* us = user_s + (size_t)g * D_USER;
        #pragma unroll
        for (int k = 0; k < D_USER; ++k) v += us[k] * W1[k * 64 + tid];
        out[4096 + tid] = f2bf(v > 0.f ? v : 0.f);
    }
}

// ------------- FALLBACK node kernel (proven R9) -----------------------------
__global__ __launch_bounds__(256) void node_fb(
    int g0,
    const float* __restrict__ x, const float* __restrict__ edge_attr,
    const float* __restrict__ user_s,
    const float* __restrict__ W_msg, const float* __restrict__ b_msg,
    const float* __restrict__ W_edge, const float* __restrict__ b_edge,
    const float* __restrict__ W_self, const float* __restrict__ b_self,
    const float* __restrict__ W1, const float* __restrict__ b1,
    const int* __restrict__ src, const int* __restrict__ dst,
    float* __restrict__ states)
{
    const int g = g0 + blockIdx.x;
    const int tid = threadIdx.x;

    __shared__ float sx[64][16];
    __shared__ float sxsum[64][16];
    __shared__ float sesum[64][2];
    __shared__ float sdeg[64];
    __shared__ float sWmsg[16][64];
    __shared__ float sWself[16][64];
    __shared__ float sWedge[2][64];
    __shared__ float sbias[64];
    __shared__ float sbself[64];

    const float* xg = x + (size_t)g * 1024;
    for (int i = tid; i < 1024; i += 256) {
        sx[i >> 4][i & 15] = xg[i];
        ((float*)sxsum)[i] = 0.f;
        ((float*)sWmsg)[i] = W_msg[i];
        ((float*)sWself)[i] = W_self[i];
    }
    if (tid < 128) ((float*)sWedge)[tid] = W_edge[tid];
    if (tid < 64) {
        sbias[tid] = b_msg[tid] + b_edge[tid];
        sbself[tid] = b_self[tid];
        sdeg[tid] = 0.f;
        sesum[tid][0] = 0.f; sesum[tid][1] = 0.f;
    }
    __syncthreads();

    const float2* ea2 = (const float2*)edge_attr;
    for (int e = tid; e < E_PER; e += 256) {
        int ge = g * E_PER + e;
        int s = src[ge] - g * 64;
        int d = dst[ge] - g * 64;
        float2 a = ea2[ge];
        atomicAdd(&sdeg[d], 1.0f);
        atomicAdd(&sesum[d][0], a.x);
        atomicAdd(&sesum[d][1], a.y);
        #pragma unroll
        for (int k = 0; k < 16; ++k) atomicAdd(&sxsum[d][k], sx[s][k]);
    }
    __syncthreads();

    float* out = states + (size_t)blockIdx.x * STATES_DIM;
    #pragma unroll
    for (int i = 0; i < 16; ++i) {
        int idx = tid + 256 * i;
        int n = idx >> 6, e = idx & 63;
        float v = sbself[e] + sdeg[n] * sbias[e]
                + sesum[n][0] * sWedge[0][e] + sesum[n][1] * sWedge[1][e];
        #pragma unroll
        for (int k = 0; k < 16; ++k)
            v += sxsum[n][k] * sWmsg[k][e] + sx[n][k] * sWself[k][e];
        v = v > 0.f ? v : 0.f;
        v = keep_bit((uint32_t)g * 4096u + (uint32_t)idx) ? v * 2.0f : 0.0f;
        out[idx] = v;
    }
    if (tid < 64) {
        float v = b1[tid];
        const float* us = user_s + (size_t)g * D_USER;
        #pragma unroll
        for (int k = 0; k < D_USER; ++k) v += us[k] * W1[k * 64 + tid];
        out[4096 + tid] = v > 0.f ? v : 0.f;
    }
}

// ------------- W [K,N] f32 -> WT [N,K] bf16 (K,N multiples of 32) -----------
__global__ __launch_bounds__(256) void transpose_w(const float* __restrict__ W,
                                                   u16* __restrict__ WT,
                                                   int K, int N) {
    __shared__ float sT[32][33];
    const int k0 = blockIdx.x * 32, n0 = blockIdx.y * 32;
    const int tr = threadIdx.x >> 5, tc = threadIdx.x & 31;
    #pragma unroll
    for (int i = 0; i < 32; i += 8)
        sT[tr + i][tc] = W[(size_t)(k0 + tr + i) * N + n0 + tc];
    __syncthreads();
    #pragma unroll
    for (int i = 0; i < 32; i += 8)
        WT[(size_t)(n0 + tr + i) * K + k0 + tc] = f2bf(sT[tc][tr + i]);
}

// ------------- barrier-free direct-register MFMA GEMM, 8-deep pipeline ------
// C[2048, N] = relu(A @ B + bias); A bf16 [2048][K], BT bf16 [N][K].
// No LDS/barriers. 8 register slots; each step MFMAs slot s then re-issues
// slot s's loads 8 k-steps ahead -> up to 24 loads in flight per wave.
// Tile 32m x 64n, 4 waves; wave = 16m x 32n. Grid = 64*(N/64), XCD-swizzled.
__global__ __launch_bounds__(256) void gemm_direct(
    const u16* __restrict__ A, const u16* __restrict__ BT,
    const float* __restrict__ bias, u16* __restrict__ C,
    int K, int N)
{
    const int bid = blockIdx.x;
    const int j = bid >> 3;
    const int mt = (bid & 7) * 8 + (j & 7);   // 0..63
    const int nt = j >> 3;                    // 0..N/64-1
    const int m0 = mt * 32, n0 = nt * 64;

    const int tid = threadIdx.x;
    const int wave = tid >> 6, lane = tid & 63;
    const int wm = (wave & 1) * 16, wn = (wave >> 1) * 32;
    const int lm = lane & 15, q = lane >> 4;

    const u16* pa  = A  + (size_t)(m0 + wm + lm) * K + q * 8;
    const u16* pb0 = BT + (size_t)(n0 + wn + lm) * K + q * 8;
    const u16* pb1 = BT + (size_t)(n0 + wn + 16 + lm) * K + q * 8;

    f32x4 acc0, acc1;
    #pragma unroll
    for (int r = 0; r < 4; ++r) { acc0[r] = 0.f; acc1[r] = 0.f; }

    short8 A0{}, A1{}, A2{}, A3{}, A4{}, A5{}, A6{}, A7{};
    short8 B00{}, B01{}, B02{}, B03{}, B04{}, B05{}, B06{}, B07{};
    short8 B10{}, B11{}, B12{}, B13{}, B14{}, B15{}, B16{}, B17{};

    int kp = 0;   // next k to prefetch (wave-uniform)

#define PREF(s) \
    if (kp < K) { A##s  = *(const short8*)pa;  \
                  B0##s = *(const short8*)pb0; \
                  B1##s = *(const short8*)pb1; \
                  pa += 32; pb0 += 32; pb1 += 32; kp += 32; }
#define STEP(s) \
    acc0 = __builtin_amdgcn_mfma_f32_16x16x32_bf16(A##s, B0##s, acc0, 0, 0, 0); \
    acc1 = __builtin_amdgcn_mfma_f32_16x16x32_bf16(A##s, B1##s, acc1, 0, 0, 0); \
    PREF(s)

    PREF(0) PREF(1) PREF(2) PREF(3) PREF(4) PREF(5) PREF(6) PREF(7)

    const int iters  = K >> 5;          // 130 (gemm1) / 16 (gemm2)
    const int groups = iters >> 3;
    const int rem    = iters & 7;
    for (int g = 0; g < groups; ++g) {
        STEP(0) STEP(1) STEP(2) STEP(3) STEP(4) STEP(5) STEP(6) STEP(7)
    }
    if (rem > 0) { STEP(0) }
    if (rem > 1) { STEP(1) }
    if (rem > 2) { STEP(2) }
    if (rem > 3) { STEP(3) }
    if (rem > 4) { STEP(4) }
    if (rem > 5) { STEP(5) }
    if (rem > 6) { STEP(6) }
#undef PREF
#undef STEP

    const float bias0 = bias[n0 + wn + lm];
    const float bias1 = bias[n0 + wn + 16 + lm];
    #pragma unroll
    for (int r = 0; r < 4; ++r) {
        int m = m0 + wm + q * 4 + r;
        float v0 = acc0[r] + bias0;
        float v1 = acc1[r] + bias1;
        v0 = v0 > 0.f ? v0 : 0.f;
        v1 = v1 > 0.f ? v1 : 0.f;
        C[(size_t)m * N + n0 + wn + lm]      = f2bf(v0);
        C[(size_t)m * N + n0 + wn + 16 + lm] = f2bf(v1);
    }
}

// ------------- f32 GEMM (proven): C = act(A @ B + bias) ---------------------
template<typename AT, typename CT, bool RELU>
__global__ __launch_bounds__(256) void gemm_any(
    const AT* __restrict__ A, const float* __restrict__ B,
    const float* __restrict__ bias, CT* __restrict__ C,
    int M, int N, int K)
{
    __shared__ float sA[32][72];
    __shared__ float sB[32][64];

    const int tid = threadIdx.x;
    const int tx = tid & 15;
    const int ty = tid >> 4;
    const int m0 = blockIdx.x * 64, n0 = blockIdx.y * 64;

    float acc[4][4] = {};

    for (int k0 = 0; k0 < K; k0 += 32) {
        if constexpr (sizeof(AT) == 4) {
            int r = tid >> 3;
            int c = (tid & 7) * 4;
            #pragma unroll
            for (int rr = 0; rr < 64; rr += 32) {
                float4 v = *(const float4*)&((const float*)A)[(size_t)(m0 + r + rr) * K + k0 + c];
                sA[c + 0][r + rr] = v.x; sA[c + 1][r + rr] = v.y;
                sA[c + 2][r + rr] = v.z; sA[c + 3][r + rr] = v.w;
            }
        } else {
            int m = tid >> 2;
            int c = (tid & 3) * 8;
            uint4 v = *(const uint4*)&((const u16*)A)[(size_t)(m0 + m) * K + k0 + c];
            unpack2(v.x, sA[c + 0][m], sA[c + 1][m]);
            unpack2(v.y, sA[c + 2][m], sA[c + 3][m]);
            unpack2(v.z, sA[c + 4][m], sA[c + 5][m]);
            unpack2(v.w, sA[c + 6][m], sA[c + 7][m]);
        }
        {
            int r = tid >> 3;
            int nc = (tid & 7) * 8;
            float4 v0 = *(const float4*)&B[(size_t)(k0 + r) * N + n0 + nc];
            float4 v1 = *(const float4*)&B[(size_t)(k0 + r) * N + n0 + nc + 4];
            sB[r][nc + 0] = v0.x; sB[r][nc + 1] = v0.y;
            sB[r][nc + 2] = v0.z; sB[r][nc + 3] = v0.w;
            sB[r][nc + 4] = v1.x; sB[r][nc + 5] = v1.y;
            sB[r][nc + 6] = v1.z; sB[r][nc + 7] = v1.w;
        }
        __syncthreads();
        #pragma unroll
        for (int kk = 0; kk < 32; ++kk) {
            float4 av = *(const float4*)&sA[kk][ty * 4];
            float4 bv = *(const float4*)&sB[kk][tx * 4];
            float a_[4] = {av.x, av.y, av.z, av.w};
            float b_[4] = {bv.x, bv.y, bv.z, bv.w};
            #pragma unroll
            for (int i = 0; i < 4; ++i)
                #pragma unroll
                for (int j = 0; j < 4; ++j)
                    acc[i][j] += a_[i] * b_[j];
        }
        __syncthreads();
    }

    #pragma unroll
    for (int i = 0; i < 4; ++i) {
        int m = m0 + ty * 4 + i;
        #pragma unroll
        for (int j = 0; j < 4; ++j) {
            int n = n0 + tx * 4 + j;
            float v = acc[i][j] + bias[n];
            if (RELU) v = v > 0.f ? v : 0.f;
            if constexpr (sizeof(CT) == 2) C[(size_t)m * N + n] = (CT)f2bf(v);
            else                           C[(size_t)m * N + n] = (CT)v;
        }
    }
}

// ------------- softmax over axis 0 ------------------------------------------
__global__ __launch_bounds__(256) void softmax_kernel(
    const float* __restrict__ logits, float* __restrict__ out)
{
    const int n = blockIdx.x;
    const int tid = threadIdx.x;
    __shared__ float sred[4];
    const int wid = tid >> 6, lane = tid & 63;

    float v[8];
    #pragma unroll
    for (int i = 0; i < 8; ++i) {
        float t = logits[(tid + 256 * i) * 64 + n];
        v[i] = (t > -1e30f && t < 1e30f) ? t : 0.0f;
    }

    float mx = -3.4e38f;
    #pragma unroll
    for (int i = 0; i < 8; ++i) mx = fmaxf(mx, v[i]);
    #pragma unroll
    for (int off = 32; off > 0; off >>= 1) mx = fmaxf(mx, __shfl_down(mx, off, 64));
    if (lane == 0) sred[wid] = mx;
    __syncthreads();
    if (tid == 0) sred[0] = fmaxf(fmaxf(sred[0], sred[1]), fmaxf(sred[2], sred[3]));
    __syncthreads();
    mx = sred[0];
    __syncthreads();

    float sum = 0.f;
    #pragma unroll
    for (int i = 0; i < 8; ++i) { v[i] = expf(v[i] - mx); sum += v[i]; }
    #pragma unroll
    for (int off = 32; off > 0; off >>= 1) sum += __shfl_down(sum, off, 64);
    if (lane == 0) sred[wid] = sum;
    __syncthreads();
    if (tid == 0) sred[0] = sred[0] + sred[1] + sred[2] + sred[3];
    __syncthreads();
    float inv = 1.0f / sred[0];
    #pragma unroll
    for (int i = 0; i < 8; ++i) out[(tid + 256 * i) * 64 + n] = v[i] * inv;
}

// ---------------------------------------------------------------------------
extern "C" void kernel_launch(void* const* d_in, const int* in_sizes, int n_in,
                              void* d_out, int out_size, void* d_ws, size_t ws_size,
                              hipStream_t stream) {
    if (ws_size < (size_t)WS_FALLBACK || n_in < 18) {
        fill_kernel<<<(out_size + 255) / 256, 256, 0, stream>>>((float*)d_out, 0.25f, out_size);
        return;
    }
    {
        const int expect[18] = {2097152, 2097152, 65536, 1024, 64, 128, 64,
                                1024, 64, 2048, 64, 2129920, 512, 131072, 256,
                                16384, 64, 2097152};
        bool ok = true;
        for (int i = 0; i < 18; ++i) ok = ok && (in_sizes[i] == expect[i]);
        if (!ok || out_size != 131072) {
            fill_kernel<<<(out_size + 255) / 256, 256, 0, stream>>>((float*)d_out, 0.125f, out_size);
            return;
        }
    }

    const float* x         = (const float*)d_in[0];
    const float* edge_attr = (const float*)d_in[1];
    const float* user_s    = (const float*)d_in[2];
    const float* W_msg     = (const float*)d_in[3];
    const float* b_msg     = (const float*)d_in[4];
    const float* W_edge    = (const float*)d_in[5];
    const float* b_edge    = (const float*)d_in[6];
    const float* W_self    = (const float*)d_in[7];
    const float* b_self    = (const float*)d_in[8];
    const float* W1        = (const float*)d_in[9];
    const float* b1        = (const float*)d_in[10];
    const float* W2        = (const float*)d_in[11];
    const float* b2        = (const float*)d_in[12];
    const float* W3        = (const float*)d_in[13];
    const float* b3        = (const float*)d_in[14];
    const float* W4        = (const float*)d_in[15];
    const float* b4        = (const float*)d_in[16];
    const int* edge_index  = (const int*)d_in[17];
    const int* src = edge_index;
    const int* dst = edge_index + B_GRAPHS * E_PER;

    float* logits = (float*)d_out;     // gemm3 -> d_out, softmax in-place
    char* ws = (char*)d_ws;

    if (ws_size >= (size_t)WS_FAST) {
        // FAST layout (peak 23,396,352 = WS_FAST, lifetime-overlapped):
        //   states bf16 : [0,          17,039,360)  dead after gemm1
        //   mask u64    : [17,039,360, 18,087,936)  dead after node_fast
        //   W2T bf16    : [17,039,360, 21,299,200)  written after node_fast
        //   h2 bf16     : [21,299,200, 23,396,352)
        //   h3 bf16     : [0,           1,048,576)  overlay (states dead)
        //   W3T bf16    : [1,048,576,   1,310,720)  overlay (states dead)
        u16*   states = (u16*)ws;
        unsigned long long* mask = (unsigned long long*)(ws + 17039360);
        u16*   W2T    = (u16*)(ws + 17039360);
        u16*   h2     = (u16*)(ws + 21299200);
        u16*   h3     = (u16*)ws;
        u16*   W3T    = (u16*)(ws + 1048576);

        mask_kernel<<<32768, 256, 0, stream>>>(mask);
        node_fast<<<B_GRAPHS, 256, 0, stream>>>(
            x, edge_attr, user_s, W_msg, b_msg, W_edge, b_edge,
            W_self, b_self, W1, b1, src, dst, mask, states);
        transpose_w<<<dim3(130, 16), 256, 0, stream>>>(W2, W2T, GK, 512);
        gemm_direct<<<512, 256, 0, stream>>>(states, W2T, b2, h2, GK, 512);
        transpose_w<<<dim3(16, 8), 256, 0, stream>>>(W3, W3T, 512, 256);
        gemm_direct<<<256, 256, 0, stream>>>(h2, W3T, b3, h3, 512, 256);
        gemm_any<u16, float, false><<<dim3(32, 1), 256, 0, stream>>>(
            h3, W4, b4, logits, B_GRAPHS, 64, 256);
        softmax_kernel<<<64, 256, 0, stream>>>(logits, logits);
    } else {
        // FALLBACK (proven R9):
        float* states = (float*)ws;
        float* h3     = (float*)ws;
        u16*   h2     = (u16*)(ws + 4259840);

        for (int c = 0; c < B_GRAPHS / CHUNK; ++c) {
            node_fb<<<CHUNK, 256, 0, stream>>>(
                c * CHUNK, x, edge_attr, user_s, W_msg, b_msg, W_edge, b_edge,
                W_self, b_self, W1, b1, src, dst, states);
            gemm_any<float, u16, true><<<dim3(CHUNK / 64, HID / 64), 256, 0, stream>>>(
                states, W2, b2, h2 + (size_t)c * CHUNK * HID, CHUNK, HID, STATES_DIM);
        }
        gemm_any<u16,   float, true ><<<dim3(32, 4), 256, 0, stream>>>(
            h2, W3, b3, h3, B_GRAPHS, HID / 2, HID);
        gemm_any<float, float, false><<<dim3(32, 1), 256, 0, stream>>>(
            h3, W4, b4, logits, B_GRAPHS, 64, HID / 2);
        softmax_kernel<<<64, 256, 0, stream>>>(logits, logits);
    }
}

// Round 15
// 225.437 us; speedup vs baseline: 1.2126x; 1.2126x over previous
//
#include <hip/hip_runtime.h>
#include <stdint.h>

#define B_GRAPHS 2048
#define CHUNK 256                    // fallback path: graphs per chunk
#define E_PER 512
#define D_USER 32
#define HID 512
#define GK 4160                      // states dim = 64*64 + 64
#define STATES_DIM 4160
#define WS_FALLBACK 6356992
#define WS_FAST 32047104

typedef unsigned short u16;
typedef unsigned int u32;
typedef __attribute__((ext_vector_type(8))) short short8;   // 8 bf16 (4 VGPRs)
typedef __attribute__((ext_vector_type(4))) float f32x4;    // MFMA accumulator

// ---------------- bf16 helpers ----------------------------------------------
__device__ __forceinline__ float bf2f(u16 b) {
    union { uint32_t u; float f; } c; c.u = ((uint32_t)b) << 16; return c.f;
}
__device__ __forceinline__ u16 f2bf(float f) {   // round-to-nearest-even
    union { float f; uint32_t u; } c; c.f = f;
    uint32_t u = c.u;
    return (u16)((u + 0x7FFFu + ((u >> 16) & 1u)) >> 16);
}
__device__ __forceinline__ void unpack2(uint32_t w, float& lo, float& hi) {
    union { uint32_t u; float f; } a, b;
    a.u = w << 16; b.u = w & 0xFFFF0000u;
    lo = a.f; hi = b.f;
}

// ---------------- threefry2x32, key=(0,42), partitionable (proven R9) -------
__device__ __forceinline__ uint32_t rotl32(uint32_t v, int r) {
    return (v << r) | (v >> (32 - r));
}
__device__ __forceinline__ void threefry_0_42(uint32_t x0, uint32_t x1,
                                              uint32_t& o0, uint32_t& o1) {
    const uint32_t ks0 = 0u, ks1 = 42u, ks2 = 0x1BD11BDAu ^ 42u;
    x0 += ks0; x1 += ks1;
#define TFR(r) { x0 += x1; x1 = rotl32(x1, (r)); x1 ^= x0; }
    TFR(13) TFR(15) TFR(26) TFR(6)
    x0 += ks1; x1 += ks2 + 1u;
    TFR(17) TFR(29) TFR(16) TFR(24)
    x0 += ks2; x1 += ks0 + 2u;
    TFR(13) TFR(15) TFR(26) TFR(6)
    x0 += ks0; x1 += ks1 + 3u;
    TFR(17) TFR(29) TFR(16) TFR(24)
    x0 += ks1; x1 += ks2 + 4u;
    TFR(13) TFR(15) TFR(26) TFR(6)
    x0 += ks2; x1 += ks0 + 5u;
#undef TFR
    o0 = x0; o1 = x1;
}
__device__ __forceinline__ bool keep_bit(uint32_t j) {
    uint32_t o0, o1;
    threefry_0_42(0u, j, o0, o1);
    return (((o0 ^ o1) >> 31) == 0u);
}

// ------------- mask kernel: 64 keep-bits per u64 word -----------------------
__global__ __launch_bounds__(256) void mask_kernel(unsigned long long* __restrict__ mask) {
    uint32_t j = blockIdx.x * 256u + threadIdx.x;    // 0 .. 8388607
    uint32_t o0, o1;
    threefry_0_42(0u, j, o0, o1);
    unsigned long long b = __ballot(((o0 ^ o1) >> 31) == 0u);
    if ((threadIdx.x & 63u) == 0u) mask[j >> 6] = b;
}

// ------------- fills --------------------------------------------------------
__global__ __launch_bounds__(256) void fill_kernel(float* __restrict__ out, float v, int n) {
    int i = blockIdx.x * 256 + threadIdx.x;
    if (i < n) out[i] = v;
}

// ------------- FAST node kernel (proven R12) --------------------------------
__global__ __launch_bounds__(256) void node_fast(
    const float* __restrict__ x, const float* __restrict__ edge_attr,
    const float* __restrict__ user_s,
    const float* __restrict__ W_msg, const float* __restrict__ b_msg,
    const float* __restrict__ W_edge, const float* __restrict__ b_edge,
    const float* __restrict__ W_self, const float* __restrict__ b_self,
    const float* __restrict__ W1, const float* __restrict__ b1,
    const int* __restrict__ src, const int* __restrict__ dst,
    const unsigned long long* __restrict__ mask,
    u16* __restrict__ states)
{
    const int g = blockIdx.x;
    const int tid = threadIdx.x;
    const int w = tid >> 6, lane = tid & 63;

    __shared__ float sx[64][16];       // [s][k]
    __shared__ u32   scnt[64][64];     // [s][d]  adjacency counts
    __shared__ float sxsum[64][16];    // [d][k]
    __shared__ float sesum[2][64];     // [j][d]
    __shared__ float sdeg[64];
    __shared__ unsigned long long smask[64];

    float rWmsg[16], rWself[16];
    #pragma unroll
    for (int k = 0; k < 16; ++k) {
        rWmsg[k]  = W_msg[k * 64 + lane];
        rWself[k] = W_self[k * 64 + lane];
    }
    const float rWe0   = W_edge[lane];
    const float rWe1   = W_edge[64 + lane];
    const float rbias  = b_msg[lane] + b_edge[lane];
    const float rbself = b_self[lane];

    const float* xg = x + (size_t)g * 1024;
    for (int i = tid; i < 1024; i += 256) ((float*)sx)[i] = xg[i];
    {
        uint4 z = make_uint4(0, 0, 0, 0);
        u32* c0 = &scnt[0][0] + tid * 16;
        *(uint4*)(c0 + 0)  = z; *(uint4*)(c0 + 4)  = z;
        *(uint4*)(c0 + 8)  = z; *(uint4*)(c0 + 12) = z;
    }
    if (tid < 64) {
        sesum[0][tid] = 0.f; sesum[1][tid] = 0.f;
        smask[tid] = mask[g * 64 + tid];
    }
    __syncthreads();

    const float2* ea2 = (const float2*)edge_attr;
    for (int e = tid; e < E_PER; e += 256) {
        int ge = g * E_PER + e;
        int s = src[ge] - g * 64;
        int d = dst[ge] - g * 64;
        float2 a = ea2[ge];
        atomicAdd(&scnt[s][d], 1u);
        atomicAdd(&sesum[0][d], a.x);
        atomicAdd(&sesum[1][d], a.y);
    }
    __syncthreads();

    {   // dense MAC: sxsum[d][kg*4..+3] = sum_s cnt[s][d] * x[s][kg*4..+3]
        const int d = tid >> 2, kg = tid & 3;
        float4 acc = make_float4(0.f, 0.f, 0.f, 0.f);
        float dg = 0.f;
        #pragma unroll 8
        for (int s = 0; s < 64; ++s) {
            float c = (float)scnt[s][d];
            dg += c;
            float4 xv = *(const float4*)&sx[s][kg * 4];
            acc.x += c * xv.x; acc.y += c * xv.y;
            acc.z += c * xv.z; acc.w += c * xv.w;
        }
        *(float4*)&sxsum[d][kg * 4] = acc;
        if (kg == 0) sdeg[d] = dg;
    }
    __syncthreads();

    u16* out = states + (size_t)g * STATES_DIM;
    #pragma unroll
    for (int i = 0; i < 16; ++i) {
        const int n = 4 * i + w;                       // wave-uniform node
        float v = rbself + sdeg[n] * rbias
                + sesum[0][n] * rWe0 + sesum[1][n] * rWe1;
        float4 s0 = *(const float4*)&sxsum[n][0];
        float4 s1 = *(const float4*)&sxsum[n][4];
        float4 s2 = *(const float4*)&sxsum[n][8];
        float4 s3 = *(const float4*)&sxsum[n][12];
        float4 x0 = *(const float4*)&sx[n][0];
        float4 x1 = *(const float4*)&sx[n][4];
        float4 x2 = *(const float4*)&sx[n][8];
        float4 x3 = *(const float4*)&sx[n][12];
        v += s0.x*rWmsg[0]  + s0.y*rWmsg[1]  + s0.z*rWmsg[2]  + s0.w*rWmsg[3]
           + s1.x*rWmsg[4]  + s1.y*rWmsg[5]  + s1.z*rWmsg[6]  + s1.w*rWmsg[7]
           + s2.x*rWmsg[8]  + s2.y*rWmsg[9]  + s2.z*rWmsg[10] + s2.w*rWmsg[11]
           + s3.x*rWmsg[12] + s3.y*rWmsg[13] + s3.z*rWmsg[14] + s3.w*rWmsg[15]
           + x0.x*rWself[0]  + x0.y*rWself[1]  + x0.z*rWself[2]  + x0.w*rWself[3]
           + x1.x*rWself[4]  + x1.y*rWself[5]  + x1.z*rWself[6]  + x1.w*rWself[7]
           + x2.x*rWself[8]  + x2.y*rWself[9]  + x2.z*rWself[10] + x2.w*rWself[11]
           + x3.x*rWself[12] + x3.y*rWself[13] + x3.z*rWself[14] + x3.w*rWself[15];
        v = v > 0.f ? v : 0.f;                         // relu
        unsigned long long m = smask[n];
        v = ((m >> lane) & 1ull) ? v * 2.0f : 0.0f;    // dropout p=0.5
        out[n * 64 + lane] = f2bf(v);
    }
    if (tid < 64) {                                    // user = relu(u @ W1 + b1)
        float v = b1[tid];
        const float* us = user_s + (size_t)g * D_USER;
        #pragma unroll
        for (int k = 0; k < D_USER; ++k) v += us[k] * W1[k * 64 + tid];
        out[4096 + tid] = f2bf(v > 0.f ? v : 0.f);
    }
}

// ------------- FALLBACK node kernel (proven R9) -----------------------------
__global__ __launch_bounds__(256) void node_fb(
    int g0,
    const float* __restrict__ x, const float* __restrict__ edge_attr,
    const float* __restrict__ user_s,
    const float* __restrict__ W_msg, const float* __restrict__ b_msg,
    const float* __restrict__ W_edge, const float* __restrict__ b_edge,
    const float* __restrict__ W_self, const float* __restrict__ b_self,
    const float* __restrict__ W1, const float* __restrict__ b1,
    const int* __restrict__ src, const int* __restrict__ dst,
    float* __restrict__ states)
{
    const int g = g0 + blockIdx.x;
    const int tid = threadIdx.x;

    __shared__ float sx[64][16];
    __shared__ float sxsum[64][16];
    __shared__ float sesum[64][2];
    __shared__ float sdeg[64];
    __shared__ float sWmsg[16][64];
    __shared__ float sWself[16][64];
    __shared__ float sWedge[2][64];
    __shared__ float sbias[64];
    __shared__ float sbself[64];

    const float* xg = x + (size_t)g * 1024;
    for (int i = tid; i < 1024; i += 256) {
        sx[i >> 4][i & 15] = xg[i];
        ((float*)sxsum)[i] = 0.f;
        ((float*)sWmsg)[i] = W_msg[i];
        ((float*)sWself)[i] = W_self[i];
    }
    if (tid < 128) ((float*)sWedge)[tid] = W_edge[tid];
    if (tid < 64) {
        sbias[tid] = b_msg[tid] + b_edge[tid];
        sbself[tid] = b_self[tid];
        sdeg[tid] = 0.f;
        sesum[tid][0] = 0.f; sesum[tid][1] = 0.f;
    }
    __syncthreads();

    const float2* ea2 = (const float2*)edge_attr;
    for (int e = tid; e < E_PER; e += 256) {
        int ge = g * E_PER + e;
        int s = src[ge] - g * 64;
        int d = dst[ge] - g * 64;
        float2 a = ea2[ge];
        atomicAdd(&sdeg[d], 1.0f);
        atomicAdd(&sesum[d][0], a.x);
        atomicAdd(&sesum[d][1], a.y);
        #pragma unroll
        for (int k = 0; k < 16; ++k) atomicAdd(&sxsum[d][k], sx[s][k]);
    }
    __syncthreads();

    float* out = states + (size_t)blockIdx.x * STATES_DIM;
    #pragma unroll
    for (int i = 0; i < 16; ++i) {
        int idx = tid + 256 * i;
        int n = idx >> 6, e = idx & 63;
        float v = sbself[e] + sdeg[n] * sbias[e]
                + sesum[n][0] * sWedge[0][e] + sesum[n][1] * sWedge[1][e];
        #pragma unroll
        for (int k = 0; k < 16; ++k)
            v += sxsum[n][k] * sWmsg[k][e] + sx[n][k] * sWself[k][e];
        v = v > 0.f ? v : 0.f;
        v = keep_bit((uint32_t)g * 4096u + (uint32_t)idx) ? v * 2.0f : 0.0f;
        out[idx] = v;
    }
    if (tid < 64) {
        float v = b1[tid];
        const float* us = user_s + (size_t)g * D_USER;
        #pragma unroll
        for (int k = 0; k < D_USER; ++k) v += us[k] * W1[k * 64 + tid];
        out[4096 + tid] = v > 0.f ? v : 0.f;
    }
}

// ------------- W [K,N] f32 -> WT [N,K] bf16 (K,N multiples of 32) -----------
__global__ __launch_bounds__(256) void transpose_w(const float* __restrict__ W,
                                                   u16* __restrict__ WT,
                                                   int K, int N) {
    __shared__ float sT[32][33];
    const int k0 = blockIdx.x * 32, n0 = blockIdx.y * 32;
    const int tr = threadIdx.x >> 5, tc = threadIdx.x & 31;
    #pragma unroll
    for (int i = 0; i < 32; i += 8)
        sT[tr + i][tc] = W[(size_t)(k0 + tr + i) * N + n0 + tc];
    __syncthreads();
    #pragma unroll
    for (int i = 0; i < 32; i += 8)
        WT[(size_t)(n0 + tr + i) * K + k0 + tc] = f2bf(sT[tc][tr + i]);
}

// ------------- split-K LDS MFMA GEMM: Cacc += A[:, ks] @ B[:, ks]^T ---------
// A bf16 [2048][K] row-major, BT bf16 [N][K]. blockIdx.y = split index; each
// split covers Ksplit (multiple of 64) of K. Partials atomicAdd'ed (f32,
// device scope) into Cacc[2048][N]. Tile 32m x 64n, 4 waves, BK=64 with
// register prefetch (structure = R12's proven 45 µs kernel; occupancy now
// 5x via the split dimension -> barrier drain amortized by resident waves).
__global__ __launch_bounds__(256) void gemm_splitk(
    const u16* __restrict__ A, const u16* __restrict__ BT,
    float* __restrict__ Cacc, int K, int Ksplit, int N)
{
    const int bid = blockIdx.x;
    const int j = bid >> 3;
    const int mt = (bid & 7) * 8 + (j & 7);   // 0..63 (XCD-swizzled)
    const int nt = j >> 3;                    // 0..N/64-1
    const int m0 = mt * 32, n0 = nt * 64;
    const int kb = blockIdx.y * Ksplit;

    __shared__ u16 sA[32][72];     // 144 B rows (16B-divisible)
    __shared__ u16 sB[64][72];

    const int tid = threadIdx.x;
    const int wave = tid >> 6, lane = tid & 63;
    const int wm = (wave & 1) * 16, wn = (wave >> 1) * 32;
    const int lm = lane & 15, q = lane >> 4;

    f32x4 acc0, acc1;
    #pragma unroll
    for (int r = 0; r < 4; ++r) { acc0[r] = 0.f; acc1[r] = 0.f; }

    const int arow = tid >> 3, aseg = (tid & 7) * 8;    // 32 rows x 8 segs
    const int brow = tid >> 2, bseg = (tid & 3) * 16;   // 64 rows x 4 segs

    const u16* pa = &A [(size_t)(m0 + arow) * K + kb + aseg];
    const u16* pb = &BT[(size_t)(n0 + brow) * K + kb + bseg];
    uint4 ra  = *(const uint4*)pa;
    uint4 rb0 = *(const uint4*)pb, rb1 = *(const uint4*)(pb + 8);

    for (int k0 = 0; k0 < Ksplit; k0 += 64) {
        __syncthreads();
        *(uint4*)&sA[arow][aseg]     = ra;
        *(uint4*)&sB[brow][bseg]     = rb0;
        *(uint4*)&sB[brow][bseg + 8] = rb1;
        __syncthreads();
        if (k0 + 64 < Ksplit) {
            pa += 64; pb += 64;
            ra  = *(const uint4*)pa;
            rb0 = *(const uint4*)pb; rb1 = *(const uint4*)(pb + 8);
        }
        #pragma unroll
        for (int kh = 0; kh < 2; ++kh) {
            short8 a  = *(const short8*)&sA[wm + lm][kh * 32 + q * 8];
            short8 b0 = *(const short8*)&sB[wn + lm][kh * 32 + q * 8];
            short8 b1 = *(const short8*)&sB[wn + 16 + lm][kh * 32 + q * 8];
            acc0 = __builtin_amdgcn_mfma_f32_16x16x32_bf16(a, b0, acc0, 0, 0, 0);
            acc1 = __builtin_amdgcn_mfma_f32_16x16x32_bf16(a, b1, acc1, 0, 0, 0);
        }
    }

    #pragma unroll
    for (int r = 0; r < 4; ++r) {
        int m = m0 + wm + q * 4 + r;
        atomicAdd(&Cacc[(size_t)m * N + n0 + wn + lm],      acc0[r]);
        atomicAdd(&Cacc[(size_t)m * N + n0 + wn + 16 + lm], acc1[r]);
    }
}

// ------------- epilogue: out = bf16(relu(acc + bias[n])) --------------------
__global__ __launch_bounds__(256) void bias_relu_cast(
    const float* __restrict__ acc, const float* __restrict__ bias,
    u16* __restrict__ out, int Nmask, int total)
{
    int i = blockIdx.x * 256 + threadIdx.x;
    if (i < total) {
        float v = acc[i] + bias[i & Nmask];
        out[i] = f2bf(v > 0.f ? v : 0.f);
    }
}

// ------------- f32 GEMM (proven): C = act(A @ B + bias) ---------------------
template<typename AT, typename CT, bool RELU>
__global__ __launch_bounds__(256) void gemm_any(
    const AT* __restrict__ A, const float* __restrict__ B,
    const float* __restrict__ bias, CT* __restrict__ C,
    int M, int N, int K)
{
    __shared__ float sA[32][72];
    __shared__ float sB[32][64];

    const int tid = threadIdx.x;
    const int tx = tid & 15;
    const int ty = tid >> 4;
    const int m0 = blockIdx.x * 64, n0 = blockIdx.y * 64;

    float acc[4][4] = {};

    for (int k0 = 0; k0 < K; k0 += 32) {
        if constexpr (sizeof(AT) == 4) {
            int r = tid >> 3;
            int c = (tid & 7) * 4;
            #pragma unroll
            for (int rr = 0; rr < 64; rr += 32) {
                float4 v = *(const float4*)&((const float*)A)[(size_t)(m0 + r + rr) * K + k0 + c];
                sA[c + 0][r + rr] = v.x; sA[c + 1][r + rr] = v.y;
                sA[c + 2][r + rr] = v.z; sA[c + 3][r + rr] = v.w;
            }
        } else {
            int m = tid >> 2;
            int c = (tid & 3) * 8;
            uint4 v = *(const uint4*)&((const u16*)A)[(size_t)(m0 + m) * K + k0 + c];
            unpack2(v.x, sA[c + 0][m], sA[c + 1][m]);
            unpack2(v.y, sA[c + 2][m], sA[c + 3][m]);
            unpack2(v.z, sA[c + 4][m], sA[c + 5][m]);
            unpack2(v.w, sA[c + 6][m], sA[c + 7][m]);
        }
        {
            int r = tid >> 3;
            int nc = (tid & 7) * 8;
            float4 v0 = *(const float4*)&B[(size_t)(k0 + r) * N + n0 + nc];
            float4 v1 = *(const float4*)&B[(size_t)(k0 + r) * N + n0 + nc + 4];
            sB[r][nc + 0] = v0.x; sB[r][nc + 1] = v0.y;
            sB[r][nc + 2] = v0.z; sB[r][nc + 3] = v0.w;
            sB[r][nc + 4] = v1.x; sB[r][nc + 5] = v1.y;
            sB[r][nc + 6] = v1.z; sB[r][nc + 7] = v1.w;
        }
        __syncthreads();
        #pragma unroll
        for (int kk = 0; kk < 32; ++kk) {
            float4 av = *(const float4*)&sA[kk][ty * 4];
            float4 bv = *(const float4*)&sB[kk][tx * 4];
            float a_[4] = {av.x, av.y, av.z, av.w};
            float b_[4] = {bv.x, bv.y, bv.z, bv.w};
            #pragma unroll
            for (int i = 0; i < 4; ++i)
                #pragma unroll
                for (int j = 0; j < 4; ++j)
                    acc[i][j] += a_[i] * b_[j];
        }
        __syncthreads();
    }

    #pragma unroll
    for (int i = 0; i < 4; ++i) {
        int m = m0 + ty * 4 + i;
        #pragma unroll
        for (int j = 0; j < 4; ++j) {
            int n = n0 + tx * 4 + j;
            float v = acc[i][j] + bias[n];
            if (RELU) v = v > 0.f ? v : 0.f;
            if constexpr (sizeof(CT) == 2) C[(size_t)m * N + n] = (CT)f2bf(v);
            else                           C[(size_t)m * N + n] = (CT)v;
        }
    }
}

// ------------- softmax over axis 0 ------------------------------------------
__global__ __launch_bounds__(256) void softmax_kernel(
    const float* __restrict__ logits, float* __restrict__ out)
{
    const int n = blockIdx.x;
    const int tid = threadIdx.x;
    __shared__ float sred[4];
    const int wid = tid >> 6, lane = tid & 63;

    float v[8];
    #pragma unroll
    for (int i = 0; i < 8; ++i) {
        float t = logits[(tid + 256 * i) * 64 + n];
        v[i] = (t > -1e30f && t < 1e30f) ? t : 0.0f;
    }

    float mx = -3.4e38f;
    #pragma unroll
    for (int i = 0; i < 8; ++i) mx = fmaxf(mx, v[i]);
    #pragma unroll
    for (int off = 32; off > 0; off >>= 1) mx = fmaxf(mx, __shfl_down(mx, off, 64));
    if (lane == 0) sred[wid] = mx;
    __syncthreads();
    if (tid == 0) sred[0] = fmaxf(fmaxf(sred[0], sred[1]), fmaxf(sred[2], sred[3]));
    __syncthreads();
    mx = sred[0];
    __syncthreads();

    float sum = 0.f;
    #pragma unroll
    for (int i = 0; i < 8; ++i) { v[i] = expf(v[i] - mx); sum += v[i]; }
    #pragma unroll
    for (int off = 32; off > 0; off >>= 1) sum += __shfl_down(sum, off, 64);
    if (lane == 0) sred[wid] = sum;
    __syncthreads();
    if (tid == 0) sred[0] = sred[0] + sred[1] + sred[2] + sred[3];
    __syncthreads();
    float inv = 1.0f / sred[0];
    #pragma unroll
    for (int i = 0; i < 8; ++i) out[(tid + 256 * i) * 64 + n] = v[i] * inv;
}

// ---------------------------------------------------------------------------
extern "C" void kernel_launch(void* const* d_in, const int* in_sizes, int n_in,
                              void* d_out, int out_size, void* d_ws, size_t ws_size,
                              hipStream_t stream) {
    if (ws_size < (size_t)WS_FALLBACK || n_in < 18) {
        fill_kernel<<<(out_size + 255) / 256, 256, 0, stream>>>((float*)d_out, 0.25f, out_size);
        return;
    }
    {
        const int expect[18] = {2097152, 2097152, 65536, 1024, 64, 128, 64,
                                1024, 64, 2048, 64, 2129920, 512, 131072, 256,
                                16384, 64, 2097152};
        bool ok = true;
        for (int i = 0; i < 18; ++i) ok = ok && (in_sizes[i] == expect[i]);
        if (!ok || out_size != 131072) {
            fill_kernel<<<(out_size + 255) / 256, 256, 0, stream>>>((float*)d_out, 0.125f, out_size);
            return;
        }
    }

    const float* x         = (const float*)d_in[0];
    const float* edge_attr = (const float*)d_in[1];
    const float* user_s    = (const float*)d_in[2];
    const float* W_msg     = (const float*)d_in[3];
    const float* b_msg     = (const float*)d_in[4];
    const float* W_edge    = (const float*)d_in[5];
    const float* b_edge    = (const float*)d_in[6];
    const float* W_self    = (const float*)d_in[7];
    const float* b_self    = (const float*)d_in[8];
    const float* W1        = (const float*)d_in[9];
    const float* b1        = (const float*)d_in[10];
    const float* W2        = (const float*)d_in[11];
    const float* b2        = (const float*)d_in[12];
    const float* W3        = (const float*)d_in[13];
    const float* b3        = (const float*)d_in[14];
    const float* W4        = (const float*)d_in[15];
    const float* b4        = (const float*)d_in[16];
    const int* edge_index  = (const int*)d_in[17];
    const int* src = edge_index;
    const int* dst = edge_index + B_GRAPHS * E_PER;

    float* logits = (float*)d_out;     // gemm3 -> d_out, softmax in-place
    char* ws = (char*)d_ws;

    if (ws_size >= (size_t)WS_FAST) {
        // FAST layout (peak 32,047,104 = WS_FAST; ws known ~256 MB from
        // harness fill counters):
        //   states bf16 : [0,          17,039,360)
        //   W2T bf16    : [17,039,360, 21,299,200)
        //   mask u64    : [21,299,200, 22,347,776)
        //   h2acc f32   : [22,347,776, 26,542,080)
        //   h2 bf16     : [26,542,080, 28,639,232)
        //   W3T bf16    : [28,639,232, 28,901,376)
        //   h3acc f32   : [28,901,376, 30,998,528)
        //   h3 bf16     : [30,998,528, 32,047,104)
        u16*   states = (u16*)ws;
        u16*   W2T    = (u16*)(ws + 17039360);
        unsigned long long* mask = (unsigned long long*)(ws + 21299200);
        float* h2acc  = (float*)(ws + 22347776);
        u16*   h2     = (u16*)(ws + 26542080);
        u16*   W3T    = (u16*)(ws + 28639232);
        float* h3acc  = (float*)(ws + 28901376);
        u16*   h3     = (u16*)(ws + 30998528);

        mask_kernel<<<32768, 256, 0, stream>>>(mask);
        node_fast<<<B_GRAPHS, 256, 0, stream>>>(
            x, edge_attr, user_s, W_msg, b_msg, W_edge, b_edge,
            W_self, b_self, W1, b1, src, dst, mask, states);
        transpose_w<<<dim3(130, 16), 256, 0, stream>>>(W2, W2T, GK, 512);
        fill_kernel<<<4096, 256, 0, stream>>>(h2acc, 0.f, B_GRAPHS * HID);
        gemm_splitk<<<dim3(512, 5), 256, 0, stream>>>(states, W2T, h2acc,
                                                      GK, 832, 512);
        bias_relu_cast<<<4096, 256, 0, stream>>>(h2acc, b2, h2, 511,
                                                 B_GRAPHS * HID);
        transpose_w<<<dim3(16, 8), 256, 0, stream>>>(W3, W3T, 512, 256);
        fill_kernel<<<2048, 256, 0, stream>>>(h3acc, 0.f, B_GRAPHS * 256);
        gemm_splitk<<<dim3(256, 2), 256, 0, stream>>>(h2, W3T, h3acc,
                                                      512, 256, 256);
        bias_relu_cast<<<2048, 256, 0, stream>>>(h3acc, b3, h3, 255,
                                                 B_GRAPHS * 256);
        gemm_any<u16, float, false><<<dim3(32, 1), 256, 0, stream>>>(
            h3, W4, b4, logits, B_GRAPHS, 64, 256);
        softmax_kernel<<<64, 256, 0, stream>>>(logits, logits);
    } else {
        // FALLBACK (proven R9):
        float* states = (float*)ws;
        float* h3     = (float*)ws;
        u16*   h2     = (u16*)(ws + 4259840);

        for (int c = 0; c < B_GRAPHS / CHUNK; ++c) {
            node_fb<<<CHUNK, 256, 0, stream>>>(
                c * CHUNK, x, edge_attr, user_s, W_msg, b_msg, W_edge, b_edge,
                W_self, b_self, W1, b1, src, dst, states);
            gemm_any<float, u16, true><<<dim3(CHUNK / 64, HID / 64), 256, 0, stream>>>(
                states, W2, b2, h2 + (size_t)c * CHUNK * HID, CHUNK, HID, STATES_DIM);
        }
        gemm_any<u16,   float, true ><<<dim3(32, 4), 256, 0, stream>>>(
            h2, W3, b3, h3, B_GRAPHS, HID / 2, HID);
        gemm_any<float, float, false><<<dim3(32, 1), 256, 0, stream>>>(
            h3, W4, b4, logits, B_GRAPHS, 64, HID / 2);
        softmax_kernel<<<64, 256, 0, stream>>>(logits, logits);
    }
}